// Round 21
// baseline (654.348 us; speedup 1.0000x reference)
//
#include <hip/hip_runtime.h>
#include <hip/hip_bf16.h>
#include <stdint.h>

#define BB 256
#define CC 1024
#define NP 25
#define EPS 1e-5f

typedef __attribute__((ext_vector_type(8))) short bf16x8;
typedef __attribute__((ext_vector_type(4))) float f32x4;
typedef unsigned int u32;

#define MFMA16(A, B, C) __builtin_amdgcn_mfma_f32_16x16x32_bf16(A, B, C, 0, 0, 0)

// async global->LDS, 16B per lane; LDS dest = wave-uniform base + lane*16
__device__ __forceinline__ void gload16(const u32* g, u32* l)
{
  __builtin_amdgcn_global_load_lds(
      (const __attribute__((address_space(1))) u32*)g,
      (__attribute__((address_space(3))) u32*)l, 16, 0, 0);
}

// ---------------------------------------------------------------- utils

__device__ __forceinline__ void head_entry(int j, int* pp, int* ww)
{
  int cnt = 0;
  for (int y1 = 0; y1 < 5; y1++)
    for (int x1 = 0; x1 < 5; x1++) {
      int p = y1 * 5 + x1;
      int y2 = y1 + 2, x2 = x1 + 2;
      if (y2 == 2 || y2 == 3)
        for (int s = 0; s < 3; s++) { if (y2 + s + 1 > 6) break; if (cnt == j) { *pp = p; *ww = 0 + s; return; } cnt++; }
      if (y1 == 3 || y1 == 4)
        for (int s = 0; s < 3; s++) { if (y1 - (s + 1) < 0) break; if (cnt == j) { *pp = p; *ww = 3 + s; return; } cnt++; }
      if (x2 == 2 || x2 == 3)
        for (int s = 0; s < 3; s++) { if (x2 + s + 1 > 6) break; if (cnt == j) { *pp = p; *ww = 6 + s; return; } cnt++; }
      if (x1 == 3 || x1 == 4)
        for (int s = 0; s < 3; s++) { if (x1 - (s + 1) < 0) break; if (cnt == j) { *pp = p; *ww = 9 + s; return; } cnt++; }
    }
}

// round-to-nearest-even bf16 (keep high 16 bits)
__device__ __forceinline__ u32 rne_hi(u32 x)
{
  return (x + 0x7FFFu + ((x >> 16) & 1u)) & 0xFFFF0000u;
}

// pack two floats as RNE bf16 pair into one u32 (a -> low, b -> high)
__device__ __forceinline__ u32 rne_pack(float a, float b)
{
  return (rne_hi(__float_as_uint(a)) >> 16) | rne_hi(__float_as_uint(b));
}

__device__ __forceinline__ float bflo(u32 u) { return __uint_as_float(u << 16); }
__device__ __forceinline__ float bfhi(u32 u) { return __uint_as_float(u & 0xFFFF0000u); }

// ------------------------------------------------- layer-1 stats from x

__global__ void k_xsums(const float* __restrict__ x, float* __restrict__ xs1,
                        float* __restrict__ xs2)
{
  int pos = blockIdx.x * 256 + threadIdx.x;   // < 50176
  float s1 = 0.f, s2 = 0.f;
  for (int b = 0; b < BB; b++) {
    float v = x[(size_t)b * 50176 + pos];
    s1 += v; s2 = fmaf(v, v, s2);
  }
  xs1[pos] = s1; xs2[pos] = s2;
}

__global__ void k_stats1(const float* __restrict__ xs1, const float* __restrict__ xs2,
                         const float* __restrict__ gam, const float* __restrict__ bet,
                         float* __restrict__ ssc, float* __restrict__ ssh)
{
  int p = blockIdx.x;
  int c = blockIdx.y * 256 + threadIdx.x;
  int y1 = p / 5, x1 = p % 5;
  float s1 = 0.f, s2 = 0.f;
  for (int dy = 0; dy < 3; dy++)
    for (int dx = 0; dx < 3; dx++) {
      int pos = c * 49 + (y1 + dy) * 7 + (x1 + dx);
      s1 += xs1[pos]; s2 += xs2[pos];
    }
  const float inv = 1.0f / 2304.0f;
  float mean = s1 * inv;
  float var  = s2 * inv - mean * mean;
  float rs   = rsqrtf(var + EPS);
  float sc   = rs * gam[c];
  ssc[(size_t)p * CC + c] = sc;
  ssh[(size_t)p * CC + c] = bet[c] - mean * sc;
}

// ---- fused transpose + BN1 affine + relu + RNE -> bufS (512-u32 rows)

__global__ void k_tsplit(const float* __restrict__ x,
                         const float* __restrict__ ssc, const float* __restrict__ ssh,
                         u32* __restrict__ bufS, int pbase, int pcount)
{
  __shared__ float tile[128][51];
  int b = blockIdx.x, cg = blockIdx.y;
  const float* src = x + (size_t)b * 50176 + (size_t)cg * 128 * 49;
  for (int idx = threadIdx.x; idx < 6272; idx += 256)
    tile[idx / 49][idx % 49] = src[idx];
  __syncthreads();
  const int t = threadIdx.x;
  const int u = t & 63;
  const int segs = pcount * 9;
  for (int sg = t >> 6; sg < segs; sg += 4) {
    int pl = sg / 9, yx = sg - pl * 9;
    int p = pbase + pl;
    int pos = (p / 5 + yx / 3) * 7 + (p % 5) + (yx % 3);
    int c0 = cg * 128 + u * 2;
    float2 sc = *(const float2*)(ssc + (size_t)p * CC + c0);
    float2 sh = *(const float2*)(ssh + (size_t)p * CC + c0);
    float v0 = fmaxf(fmaf(tile[u * 2][pos],     sc.x, sh.x), 0.f);
    float v1 = fmaxf(fmaf(tile[u * 2 + 1][pos], sc.y, sh.y), 0.f);
    bufS[((size_t)pl * 2304 + b * 9 + yx) * 512 + cg * 64 + u] = rne_pack(v0, v1);
  }
}

// ---------- weights: RNE hi-only layout (512-u32 rows, slab = 16 u32)

__global__ void k_wsplit_rn(const float* __restrict__ w, u32* __restrict__ dst, int total)
{
  int g = blockIdx.x * 256 + threadIdx.x;
  if (g >= total) return;
  int row = g >> 9;
  int idx = g & 511;
  const float* src = w + ((size_t)row << 10) + 2 * idx;
  dst[g] = rne_pack(src[0], src[1]);
}

// ------------- conv2-A: BN2 affine + relu + RNE (bf16-pair src -> bufS)

__global__ void k_absplit(const u32* __restrict__ src,
                          const float* __restrict__ ssc, const float* __restrict__ ssh,
                          u32* __restrict__ dst, int pbase)
{
  int r = blockIdx.x * 8 + (threadIdx.x >> 5);   // local row
  int slab = threadIdx.x & 31;
  int pg = pbase + r / 2304;
  const u32* su = src + (size_t)r * 512 + slab * 16;
  const float* scp = ssc + (size_t)pg * CC + slab * 32;
  const float* shp = ssh + (size_t)pg * CC + slab * 32;
  u32 hi[16];
  #pragma unroll
  for (int j = 0; j < 8; j++) {
    u32 p0 = su[2 * j], p1 = su[2 * j + 1];
    float4 f = { bflo(p0), bfhi(p0), bflo(p1), bfhi(p1) };
    float4 s = *(const float4*)(scp + 4 * j);
    float4 h = *(const float4*)(shp + 4 * j);
    f.x = fmaxf(fmaf(f.x, s.x, h.x), 0.f);
    f.y = fmaxf(fmaf(f.y, s.y, h.y), 0.f);
    f.z = fmaxf(fmaf(f.z, s.z, h.z), 0.f);
    f.w = fmaxf(fmaf(f.w, s.w, h.w), 0.f);
    hi[2 * j]     = rne_pack(f.x, f.y);
    hi[2 * j + 1] = rne_pack(f.z, f.w);
  }
  u32* op = dst + (size_t)r * 512 + slab * 16;
  *(uint4*)(op + 0)  = make_uint4(hi[0], hi[1], hi[2], hi[3]);
  *(uint4*)(op + 4)  = make_uint4(hi[4], hi[5], hi[6], hi[7]);
  *(uint4*)(op + 8)  = make_uint4(hi[8], hi[9], hi[10], hi[11]);
  *(uint4*)(op + 12) = make_uint4(hi[12], hi[13], hi[14], hi[15]);
}

// ------------------- finalize BN stats from per-mblock partials (18/patch)

__global__ void k_statsfin(const float* __restrict__ part, const float* __restrict__ gam,
                           const float* __restrict__ bet, float* __restrict__ ssc,
                           float* __restrict__ ssh, int pbase)
{
  int pl = blockIdx.x;
  int c  = blockIdx.y * 256 + threadIdx.x;
  float s1 = 0.f, s2 = 0.f;
  for (int mb = 0; mb < 18; mb++) {
    const float* pp = part + ((size_t)(pl * 18 + mb) * CC + c) * 2;
    s1 += pp[0]; s2 += pp[1];
  }
  const float inv = 1.0f / 2304.0f;
  float mean = s1 * inv;
  float var  = s2 * inv - mean * mean;
  float rs   = rsqrtf(var + EPS);
  float sc   = rs * gam[c];
  int pg = pbase + pl;
  ssc[(size_t)pg * CC + c] = sc;
  ssh[(size_t)pg * CC + c] = bet[c] - mean * sc;
}

// ---- BN3 affine+relu + 3x3 mean pooling; input bf16-pairs, output RNE hi-only

__global__ void k_pool(const u32* __restrict__ h, const float* __restrict__ ssc,
                       const float* __restrict__ ssh, u32* __restrict__ apool, int pbase)
{
  int row = blockIdx.x;                 // local: pl*256 + b
  int pl = row >> 8;
  int pg = pbase + pl;
  int c = threadIdx.x * 4;
  float4 sc = *(const float4*)(ssc + (size_t)pg * CC + c);
  float4 sh = *(const float4*)(ssh + (size_t)pg * CC + c);
  const u32* hp = h + (size_t)row * 9 * 512 + (c >> 1);
  float4 s = {0.f, 0.f, 0.f, 0.f};
  #pragma unroll
  for (int yx = 0; yx < 9; yx++) {
    uint2 pp = *(const uint2*)(hp + (size_t)yx * 512);
    float4 v = { bflo(pp.x), bfhi(pp.x), bflo(pp.y), bfhi(pp.y) };
    s.x += fmaxf(fmaf(v.x, sc.x, sh.x), 0.f);
    s.y += fmaxf(fmaf(v.y, sc.y, sh.y), 0.f);
    s.z += fmaxf(fmaf(v.z, sc.z, sh.z), 0.f);
    s.w += fmaxf(fmaf(v.w, sc.w, sh.w), 0.f);
  }
  const float inv9 = 1.0f / 9.0f;
  uint2 o = { rne_pack(s.x * inv9, s.y * inv9), rne_pack(s.z * inv9, s.w * inv9) };
  u32* op = apool + ((size_t)(pbase * 256) + row) * 512 + (c >> 1);
  *(uint2*)op = o;
}

// ------------------------------------------------------------ MFMA GEMM core
// C[m][n] = sum_k A[m][k] * B[n][k] + bias[n]; A and B both RNE hi-only bf16
// (512-u32 rows, granule g^((row>>1)&3), 2-way max), staged via global_load_lds.
// 3-slab circular LDS buffer with COUNTED vmcnt (T4): per iteration
//   {s_waitcnt vmcnt(4); s_barrier}  -- slab-it loads complete, it+1/it+2 in flight
//   stage slab it+2 (after barrier: its buffer was last read at it-1)
//   compute slab it.
// Each wave issues exactly 4 gloads/stage -> outstanding=8 at the wait.
// OUT=0 fp32 rows; OUT=1 RNE bf16-pair rows (512-u32, lane-pair shfl pack).
// STATS: per-block column sum/sumsq -> partOut[mb][col][2]. Scratch aliases sA[0].

template<int OUT, bool STATS>
__device__ __forceinline__ void mg_body(
    const u32* __restrict__ Agl, const u32* __restrict__ Bp,
    const float* __restrict__ bias, void* __restrict__ Cptr,
    int m0, int n0, float* __restrict__ partOut, int mb)
{
  __shared__ u32 sA[3][128 * 16];
  __shared__ u32 sB[3][128 * 16];

  const int t = threadIdx.x;
  const int l = t & 63, wv = t >> 6;
  const int lr = l & 15, lk = l >> 4;
  const int wm = (wv >> 1) * 64, wn = (wv & 1) * 64;

  // fragment read offsets (u32) with granule XOR swizzle
  int fAh[4], fBh[4];
  #pragma unroll
  for (int i = 0; i < 4; i++) {
    int Ra = wm + i * 16 + lr;
    int Rb = wn + i * 16 + lr;
    fAh[i] = Ra * 16 + ((lk ^ ((Ra >> 1) & 3)) << 2);
    fBh[i] = Rb * 16 + ((lk ^ ((Rb >> 1) & 3)) << 2);
  }

  // gload addressing: 2 chunks of 16 rows (16-u32 rows) per operand
  int grow[2], gg[2], gdst[2];
  #pragma unroll
  for (int q = 0; q < 2; q++) {
    int rr = wv * 32 + q * 16 + (l >> 2);
    grow[q] = rr;
    gg[q] = (((l & 3) ^ ((rr >> 1) & 3)) << 2);
    gdst[q] = (wv * 32 + q * 16) * 16;
  }
  const u32* Brow = Bp + (size_t)n0 * 512;
  const u32* Agr  = Agl + (size_t)m0 * 512;

  f32x4 acc[4][4];
  #pragma unroll
  for (int i = 0; i < 4; i++)
    #pragma unroll
    for (int j = 0; j < 4; j++) { f32x4 z = {0.f, 0.f, 0.f, 0.f}; acc[i][j] = z; }

  // prologue: stage slabs 0 and 1 (8 loads in flight)
  #pragma unroll
  for (int s0 = 0; s0 < 2; s0++) {
    const int so = s0 << 4;
    #pragma unroll
    for (int q = 0; q < 2; q++) {
      gload16(Brow + (size_t)grow[q] * 512 + so + gg[q], &sB[s0][gdst[q]]);
      gload16(Agr + (size_t)grow[q] * 512 + so + gg[q], &sA[s0][gdst[q]]);
    }
  }

  int cur = 0, stg = 2;
  #pragma unroll 1
  for (int it = 0; it < 32; ++it) {
    // counted wait + barrier in ONE asm (no reordering across it):
    // slab-it loads (oldest 4) complete; newer prefetches stay in flight.
    if (it < 31) asm volatile("s_waitcnt vmcnt(4)\n\ts_barrier" ::: "memory");
    else         asm volatile("s_waitcnt vmcnt(0)\n\ts_barrier" ::: "memory");
    if (it < 30) {
      const int so = (it + 2) << 4;
      u32* dA = &sA[stg][0];
      u32* dB = &sB[stg][0];
      #pragma unroll
      for (int q = 0; q < 2; q++) {
        gload16(Brow + (size_t)grow[q] * 512 + so + gg[q], &dB[gdst[q]]);
        gload16(Agr + (size_t)grow[q] * 512 + so + gg[q], &dA[gdst[q]]);
      }
    }
    const u32* rA = &sA[cur][0];
    const u32* rB = &sB[cur][0];
    bf16x8 Ah[4], Bh[4];
    #pragma unroll
    for (int i = 0; i < 4; i++) {
      Ah[i] = *(const bf16x8*)&rA[fAh[i]];
      Bh[i] = *(const bf16x8*)&rB[fBh[i]];
    }
    #pragma unroll
    for (int i = 0; i < 4; i++)
      #pragma unroll
      for (int j = 0; j < 4; j++)
        acc[i][j] = MFMA16(Ah[i], Bh[j], acc[i][j]);
    cur = (cur == 2) ? 0 : cur + 1;
    stg = (stg == 2) ? 0 : stg + 1;
  }

  // epilogue: D row = lk*4 + reg, col = lr [m89 layout]; optional col stats
  float* Cf = (float*)Cptr;
  u32*   Cu = (u32*)Cptr;
  float st1[4], st2[4];
  #pragma unroll
  for (int j = 0; j < 4; j++) { st1[j] = 0.f; st2[j] = 0.f; }
  #pragma unroll
  for (int j = 0; j < 4; j++) {
    int ocol = n0 + wn + j * 16 + lr;
    float bj = bias[ocol];
    #pragma unroll
    for (int i = 0; i < 4; i++) {
      int orow = m0 + wm + i * 16 + lk * 4;
      #pragma unroll
      for (int reg = 0; reg < 4; reg++) {
        float v = acc[i][j][reg] + bj;
        if (STATS) { st1[j] += v; st2[j] = fmaf(v, v, st2[j]); }
        int row = orow + reg;
        if (OUT == 0) {
          Cf[(size_t)row * CC + ocol] = v;
        } else {
          float pv = __shfl_xor(v, 1);
          if (!(lr & 1))
            Cu[(size_t)row * 512 + (ocol >> 1)] = rne_pack(v, pv);
        }
      }
    }
  }
  if (STATS) {
    float* srb = (float*)&sA[0][0];   // sA[0] last read at it=30; safe after epilogue barrier below
    #pragma unroll
    for (int j = 0; j < 4; j++) {
      st1[j] += __shfl_xor(st1[j], 16, 64);
      st1[j] += __shfl_xor(st1[j], 32, 64);
      st2[j] += __shfl_xor(st2[j], 16, 64);
      st2[j] += __shfl_xor(st2[j], 32, 64);
    }
    __syncthreads();                  // all waves past K-loop before reusing sA[0]
    if (lk == 0) {
      #pragma unroll
      for (int j = 0; j < 4; j++) {
        srb[wv * 64 + j * 16 + lr]       = st1[j];
        srb[256 + wv * 64 + j * 16 + lr] = st2[j];
      }
    }
    __syncthreads();
    if (t < 128) {
      int ch = t >> 6, c6 = t & 63;
      float a1 = srb[ch * 64 + c6] + srb[(ch + 2) * 64 + c6];
      float a2 = srb[256 + ch * 64 + c6] + srb[256 + (ch + 2) * 64 + c6];
      float2 o = { a1, a2 };
      *(float2*)(partOut + ((size_t)mb * CC + n0 + t) * 2) = o;
    }
  }
}

// conv wrapper with grouped block swizzle (SWZ_G m-tiles x 8 n-tiles per group)
#define SWZ_G 64

template<int OUT, bool STATS>
__global__ __launch_bounds__(256, 2)
void k_mg(const u32* __restrict__ A, const u32* __restrict__ Bp,
          const float* __restrict__ bias, void* __restrict__ Cptr,
          int mtiles, float* __restrict__ partOut)
{
  int id = blockIdx.y * gridDim.x + blockIdx.x;
  int g = id / (SWZ_G * 8);
  int rem = id - g * (SWZ_G * 8);
  int gsz = mtiles - g * SWZ_G; if (gsz > SWZ_G) gsz = SWZ_G;
  int mt = g * SWZ_G + rem % gsz;
  int nt = rem / gsz;
  mg_body<OUT, STATS>(A, Bp, bias, Cptr, mt * 128, nt * 128, partOut, mt);
}

__global__ __launch_bounds__(256, 2)
void k_heads(const u32* __restrict__ ctxp, const u32* __restrict__ wplh,
             const float* __restrict__ lb, float* __restrict__ out)
{
  int p, w;
  head_entry(blockIdx.y, &p, &w);
  mg_body<0, false>(ctxp + (size_t)p * BB * 512,
                    wplh + (size_t)w * 524288,
                    lb + (size_t)w * CC,
                    out + (size_t)blockIdx.y * BB * CC,
                    (blockIdx.x >> 3) * 128, (blockIdx.x & 7) * 128,
                    nullptr, 0);
}

// ---------------------------------------------------------------- launch

extern "C" void kernel_launch(void* const* d_in, const int* in_sizes, int n_in,
                              void* d_out, int out_size, void* d_ws, size_t ws_size,
                              hipStream_t stream)
{
  const float* x   = (const float*)d_in[0];
  const float* bng = (const float*)d_in[1];
  const float* bnb = (const float*)d_in[2];
  const float* cw  = (const float*)d_in[3];
  const float* cb  = (const float*)d_in[4];
  const float* lw  = (const float*)d_in[5];
  const float* lb  = (const float*)d_in[6];
  float* out = (float*)d_out;

  const size_t W = ws_size / 4;           // 4-byte words
  const size_t SZ_WHI  = 3ull * 524288;   // conv weights, RNE hi-only
  const size_t SZ_WPL  = 12ull * 524288;  // head weights, RNE hi-only
  const size_t SZ_PS   = 6400ull * 512;   // pooled RNE hi-only (u32)
  const size_t SZ_CTXP = 6400ull * 512;   // ctx RNE hi-only (u32)
  const size_t SZ_XS   = 50176;
  const size_t SZ_SS   = 25ull * 1024;

  auto need = [&](int pc) -> size_t {
    return SZ_WHI + SZ_WPL
         + 2ull * pc * 2304 * 512           // bufS + bufO (u32)
         + SZ_PS + SZ_CTXP + 2 * SZ_XS + 2 * SZ_SS
         + (size_t)pc * 18 * 1024 * 2;
  };
  int PC;
  if      (W >= need(25)) PC = 25;
  else if (W >= need(5))  PC = 5;
  else                    PC = 1;

  u32*   whi    = (u32*)d_ws;
  u32*   wpl    = whi + SZ_WHI;
  u32*   bufS   = wpl + SZ_WPL;
  u32*   bufO   = bufS + (size_t)PC * 2304 * 512;
  u32*   pooledS= bufO + (size_t)PC * 2304 * 512;
  u32*   ctxp   = pooledS + SZ_PS;
  float* xs1    = (float*)(ctxp + SZ_CTXP);
  float* xs2    = xs1 + SZ_XS;
  float* ssc    = xs2 + SZ_XS;
  float* ssh    = ssc + SZ_SS;
  float* part   = ssh + SZ_SS;

  // weight pre-split: conv + heads, both RNE hi-only
  k_wsplit_rn<<<(int)(SZ_WHI / 256), 256, 0, stream>>>(cw, whi, (int)SZ_WHI);
  k_wsplit_rn<<<(int)(SZ_WPL / 256), 256, 0, stream>>>(lw, wpl, (int)SZ_WPL);
  k_xsums<<<196, 256, 0, stream>>>(x, xs1, xs2);
  k_stats1<<<dim3(25, 4), 256, 0, stream>>>(xs1, xs2, bng, bnb, ssc, ssh);

  for (int pbase = 0; pbase < NP; pbase += PC) {
    const int rows = PC * 2304;
    const int mtiles = PC * 18;
    const dim3 gconv(mtiles, 8);
    // A1: fused transpose + BN1 + relu + RNE -> bufS
    k_tsplit<<<dim3(256, 8), 256, 0, stream>>>(x, ssc, ssh, bufS, pbase, PC);
    // conv1: bufS -> bufO (bf16-pairs), col stats -> part
    k_mg<1, true><<<gconv, 256, 0, stream>>>(bufS, whi, cb, bufO, mtiles, part);
    k_statsfin<<<dim3(PC, 4), 256, 0, stream>>>(part, bng + CC, bnb + CC, ssc, ssh, pbase);
    // A2: BN2+relu+RNE from bufO -> bufS
    k_absplit<<<rows / 8, 256, 0, stream>>>(bufO, ssc, ssh, bufS, pbase);
    // conv2: bufS -> bufO (bf16-pairs), stats -> part
    k_mg<1, true><<<gconv, 256, 0, stream>>>(bufS, whi + 524288, cb + CC,
                                             bufO, mtiles, part);
    k_statsfin<<<dim3(PC, 4), 256, 0, stream>>>(part, bng + 2 * CC, bnb + 2 * CC, ssc, ssh, pbase);
    // BN3+relu+pool from bufO, RNE output -> pooledS slice
    k_pool<<<PC * 256, 256, 0, stream>>>(bufO, ssc, ssh, pooledS, pbase);
  }

  // conv3 over all pooled rows -> ctxp (RNE bf16-pairs, direct)
  k_mg<1, false><<<dim3(50, 8), 256, 0, stream>>>(pooledS, whi + 2 * 524288,
                                                  cb + 2 * CC, ctxp, 50, nullptr);
  // heads: A = ctxp (RNE), B = head weights (RNE), 1 product
  k_heads<<<dim3(16, 120), 256, 0, stream>>>(ctxp, wpl, lb, out);
}

// Round 22
// 633.276 us; speedup vs baseline: 1.0333x; 1.0333x over previous
//
#include <hip/hip_runtime.h>
#include <hip/hip_bf16.h>
#include <stdint.h>

#define BB 256
#define CC 1024
#define NP 25
#define EPS 1e-5f

typedef __attribute__((ext_vector_type(8))) short bf16x8;
typedef __attribute__((ext_vector_type(4))) float f32x4;
typedef unsigned int u32;

#define MFMA16(A, B, C) __builtin_amdgcn_mfma_f32_16x16x32_bf16(A, B, C, 0, 0, 0)

// async global->LDS, 16B per lane; LDS dest = wave-uniform base + lane*16
__device__ __forceinline__ void gload16(const u32* g, u32* l)
{
  __builtin_amdgcn_global_load_lds(
      (const __attribute__((address_space(1))) u32*)g,
      (__attribute__((address_space(3))) u32*)l, 16, 0, 0);
}

// ---------------------------------------------------------------- utils

__device__ __forceinline__ void head_entry(int j, int* pp, int* ww)
{
  int cnt = 0;
  for (int y1 = 0; y1 < 5; y1++)
    for (int x1 = 0; x1 < 5; x1++) {
      int p = y1 * 5 + x1;
      int y2 = y1 + 2, x2 = x1 + 2;
      if (y2 == 2 || y2 == 3)
        for (int s = 0; s < 3; s++) { if (y2 + s + 1 > 6) break; if (cnt == j) { *pp = p; *ww = 0 + s; return; } cnt++; }
      if (y1 == 3 || y1 == 4)
        for (int s = 0; s < 3; s++) { if (y1 - (s + 1) < 0) break; if (cnt == j) { *pp = p; *ww = 3 + s; return; } cnt++; }
      if (x2 == 2 || x2 == 3)
        for (int s = 0; s < 3; s++) { if (x2 + s + 1 > 6) break; if (cnt == j) { *pp = p; *ww = 6 + s; return; } cnt++; }
      if (x1 == 3 || x1 == 4)
        for (int s = 0; s < 3; s++) { if (x1 - (s + 1) < 0) break; if (cnt == j) { *pp = p; *ww = 9 + s; return; } cnt++; }
    }
}

// round-to-nearest-even bf16 (keep high 16 bits)
__device__ __forceinline__ u32 rne_hi(u32 x)
{
  return (x + 0x7FFFu + ((x >> 16) & 1u)) & 0xFFFF0000u;
}

// pack two floats as RNE bf16 pair into one u32 (a -> low, b -> high)
__device__ __forceinline__ u32 rne_pack(float a, float b)
{
  return (rne_hi(__float_as_uint(a)) >> 16) | rne_hi(__float_as_uint(b));
}

__device__ __forceinline__ float bflo(u32 u) { return __uint_as_float(u << 16); }
__device__ __forceinline__ float bfhi(u32 u) { return __uint_as_float(u & 0xFFFF0000u); }

// ------------------------------------------------- layer-1 stats from x

__global__ void k_xsums(const float* __restrict__ x, float* __restrict__ xs1,
                        float* __restrict__ xs2)
{
  int pos = blockIdx.x * 256 + threadIdx.x;   // < 50176
  float s1 = 0.f, s2 = 0.f;
  for (int b = 0; b < BB; b++) {
    float v = x[(size_t)b * 50176 + pos];
    s1 += v; s2 = fmaf(v, v, s2);
  }
  xs1[pos] = s1; xs2[pos] = s2;
}

__global__ void k_stats1(const float* __restrict__ xs1, const float* __restrict__ xs2,
                         const float* __restrict__ gam, const float* __restrict__ bet,
                         float* __restrict__ ssc, float* __restrict__ ssh)
{
  int p = blockIdx.x;
  int c = blockIdx.y * 256 + threadIdx.x;
  int y1 = p / 5, x1 = p % 5;
  float s1 = 0.f, s2 = 0.f;
  for (int dy = 0; dy < 3; dy++)
    for (int dx = 0; dx < 3; dx++) {
      int pos = c * 49 + (y1 + dy) * 7 + (x1 + dx);
      s1 += xs1[pos]; s2 += xs2[pos];
    }
  const float inv = 1.0f / 2304.0f;
  float mean = s1 * inv;
  float var  = s2 * inv - mean * mean;
  float rs   = rsqrtf(var + EPS);
  float sc   = rs * gam[c];
  ssc[(size_t)p * CC + c] = sc;
  ssh[(size_t)p * CC + c] = bet[c] - mean * sc;
}

// ---- fused transpose + BN1 affine + relu + RNE -> bufS (512-u32 rows)

__global__ void k_tsplit(const float* __restrict__ x,
                         const float* __restrict__ ssc, const float* __restrict__ ssh,
                         u32* __restrict__ bufS, int pbase, int pcount)
{
  __shared__ float tile[128][51];
  int b = blockIdx.x, cg = blockIdx.y;
  const float* src = x + (size_t)b * 50176 + (size_t)cg * 128 * 49;
  for (int idx = threadIdx.x; idx < 6272; idx += 256)
    tile[idx / 49][idx % 49] = src[idx];
  __syncthreads();
  const int t = threadIdx.x;
  const int u = t & 63;
  const int segs = pcount * 9;
  for (int sg = t >> 6; sg < segs; sg += 4) {
    int pl = sg / 9, yx = sg - pl * 9;
    int p = pbase + pl;
    int pos = (p / 5 + yx / 3) * 7 + (p % 5) + (yx % 3);
    int c0 = cg * 128 + u * 2;
    float2 sc = *(const float2*)(ssc + (size_t)p * CC + c0);
    float2 sh = *(const float2*)(ssh + (size_t)p * CC + c0);
    float v0 = fmaxf(fmaf(tile[u * 2][pos],     sc.x, sh.x), 0.f);
    float v1 = fmaxf(fmaf(tile[u * 2 + 1][pos], sc.y, sh.y), 0.f);
    bufS[((size_t)pl * 2304 + b * 9 + yx) * 512 + cg * 64 + u] = rne_pack(v0, v1);
  }
}

// ---------- weights: RNE hi-only layout (512-u32 rows, slab = 16 u32)

__global__ void k_wsplit_rn(const float* __restrict__ w, u32* __restrict__ dst, int total)
{
  int g = blockIdx.x * 256 + threadIdx.x;
  if (g >= total) return;
  int row = g >> 9;
  int idx = g & 511;
  const float* src = w + ((size_t)row << 10) + 2 * idx;
  dst[g] = rne_pack(src[0], src[1]);
}

// ------------- conv2-A: BN2 affine + relu + RNE (bf16-pair src -> bufS)

__global__ void k_absplit(const u32* __restrict__ src,
                          const float* __restrict__ ssc, const float* __restrict__ ssh,
                          u32* __restrict__ dst, int pbase)
{
  int r = blockIdx.x * 8 + (threadIdx.x >> 5);   // local row
  int slab = threadIdx.x & 31;
  int pg = pbase + r / 2304;
  const u32* su = src + (size_t)r * 512 + slab * 16;
  const float* scp = ssc + (size_t)pg * CC + slab * 32;
  const float* shp = ssh + (size_t)pg * CC + slab * 32;
  u32 hi[16];
  #pragma unroll
  for (int j = 0; j < 8; j++) {
    u32 p0 = su[2 * j], p1 = su[2 * j + 1];
    float4 f = { bflo(p0), bfhi(p0), bflo(p1), bfhi(p1) };
    float4 s = *(const float4*)(scp + 4 * j);
    float4 h = *(const float4*)(shp + 4 * j);
    f.x = fmaxf(fmaf(f.x, s.x, h.x), 0.f);
    f.y = fmaxf(fmaf(f.y, s.y, h.y), 0.f);
    f.z = fmaxf(fmaf(f.z, s.z, h.z), 0.f);
    f.w = fmaxf(fmaf(f.w, s.w, h.w), 0.f);
    hi[2 * j]     = rne_pack(f.x, f.y);
    hi[2 * j + 1] = rne_pack(f.z, f.w);
  }
  u32* op = dst + (size_t)r * 512 + slab * 16;
  *(uint4*)(op + 0)  = make_uint4(hi[0], hi[1], hi[2], hi[3]);
  *(uint4*)(op + 4)  = make_uint4(hi[4], hi[5], hi[6], hi[7]);
  *(uint4*)(op + 8)  = make_uint4(hi[8], hi[9], hi[10], hi[11]);
  *(uint4*)(op + 12) = make_uint4(hi[12], hi[13], hi[14], hi[15]);
}

// ------------------- finalize BN stats from per-mblock partials (18/patch)

__global__ void k_statsfin(const float* __restrict__ part, const float* __restrict__ gam,
                           const float* __restrict__ bet, float* __restrict__ ssc,
                           float* __restrict__ ssh, int pbase)
{
  int pl = blockIdx.x;
  int c  = blockIdx.y * 256 + threadIdx.x;
  float s1 = 0.f, s2 = 0.f;
  for (int mb = 0; mb < 18; mb++) {
    const float* pp = part + ((size_t)(pl * 18 + mb) * CC + c) * 2;
    s1 += pp[0]; s2 += pp[1];
  }
  const float inv = 1.0f / 2304.0f;
  float mean = s1 * inv;
  float var  = s2 * inv - mean * mean;
  float rs   = rsqrtf(var + EPS);
  float sc   = rs * gam[c];
  int pg = pbase + pl;
  ssc[(size_t)pg * CC + c] = sc;
  ssh[(size_t)pg * CC + c] = bet[c] - mean * sc;
}

// ---- BN3 affine+relu + 3x3 mean pooling; input bf16-pairs, output RNE hi-only

__global__ void k_pool(const u32* __restrict__ h, const float* __restrict__ ssc,
                       const float* __restrict__ ssh, u32* __restrict__ apool, int pbase)
{
  int row = blockIdx.x;                 // local: pl*256 + b
  int pl = row >> 8;
  int pg = pbase + pl;
  int c = threadIdx.x * 4;
  float4 sc = *(const float4*)(ssc + (size_t)pg * CC + c);
  float4 sh = *(const float4*)(ssh + (size_t)pg * CC + c);
  const u32* hp = h + (size_t)row * 9 * 512 + (c >> 1);
  float4 s = {0.f, 0.f, 0.f, 0.f};
  #pragma unroll
  for (int yx = 0; yx < 9; yx++) {
    uint2 pp = *(const uint2*)(hp + (size_t)yx * 512);
    float4 v = { bflo(pp.x), bfhi(pp.x), bflo(pp.y), bfhi(pp.y) };
    s.x += fmaxf(fmaf(v.x, sc.x, sh.x), 0.f);
    s.y += fmaxf(fmaf(v.y, sc.y, sh.y), 0.f);
    s.z += fmaxf(fmaf(v.z, sc.z, sh.z), 0.f);
    s.w += fmaxf(fmaf(v.w, sc.w, sh.w), 0.f);
  }
  const float inv9 = 1.0f / 9.0f;
  uint2 o = { rne_pack(s.x * inv9, s.y * inv9), rne_pack(s.z * inv9, s.w * inv9) };
  u32* op = apool + ((size_t)(pbase * 256) + row) * 512 + (c >> 1);
  *(uint2*)op = o;
}

// ------------------------------------------------------------ MFMA GEMM core
// C[m][n] = sum_k A[m][k] * B[n][k] + bias[n]; A and B both RNE hi-only bf16
// (512-u32 rows, granule g^((row>>1)&3), 2-way max), staged via global_load_lds.
// 1 MFMA product per frag-pair. Used by convs AND heads (A=ctx RNE).
// OUT=0 fp32 rows; OUT=1 RNE bf16-pair rows (512-u32, lane-pair shfl pack).
// STATS: per-block column sum/sumsq -> partOut[mb][col][2].
// Stats scratch aliases sA (dead after the K-loop) -> LDS = 32 KB.

template<int OUT, bool STATS>
__device__ __forceinline__ void mg_body(
    const u32* __restrict__ Agl, const u32* __restrict__ Bp,
    const float* __restrict__ bias, void* __restrict__ Cptr,
    int m0, int n0, float* __restrict__ partOut, int mb)
{
  __shared__ u32 sA[2][128 * 16];
  __shared__ u32 sB[2][128 * 16];

  const int t = threadIdx.x;
  const int l = t & 63, wv = t >> 6;
  const int lr = l & 15, lk = l >> 4;
  const int wm = (wv >> 1) * 64, wn = (wv & 1) * 64;

  // fragment read offsets (u32) with granule XOR swizzle
  int fAh[4], fBh[4];
  #pragma unroll
  for (int i = 0; i < 4; i++) {
    int Ra = wm + i * 16 + lr;
    int Rb = wn + i * 16 + lr;
    fAh[i] = Ra * 16 + ((lk ^ ((Ra >> 1) & 3)) << 2);
    fBh[i] = Rb * 16 + ((lk ^ ((Rb >> 1) & 3)) << 2);
  }

  // gload addressing: 2 chunks of 16 rows (16-u32 rows) per operand
  int grow[2], gg[2], gdst[2];
  #pragma unroll
  for (int q = 0; q < 2; q++) {
    int rr = wv * 32 + q * 16 + (l >> 2);
    grow[q] = rr;
    gg[q] = (((l & 3) ^ ((rr >> 1) & 3)) << 2);
    gdst[q] = (wv * 32 + q * 16) * 16;
  }
  const u32* Brow = Bp + (size_t)n0 * 512;
  const u32* Agr  = Agl + (size_t)m0 * 512;

  f32x4 acc[4][4];
  #pragma unroll
  for (int i = 0; i < 4; i++)
    #pragma unroll
    for (int j = 0; j < 4; j++) { f32x4 z = {0.f, 0.f, 0.f, 0.f}; acc[i][j] = z; }

  // prologue: stage slab 0
  #pragma unroll
  for (int q = 0; q < 2; q++) {
    gload16(Brow + (size_t)grow[q] * 512 + gg[q], &sB[0][gdst[q]]);
    gload16(Agr + (size_t)grow[q] * 512 + gg[q], &sA[0][gdst[q]]);
  }
  __syncthreads();

  #pragma unroll 1
  for (int it = 0; it < 32; ++it) {
    const int cur = it & 1, nxt = cur ^ 1;
    const bool pf = (it < 31);
    if (pf) {
      const int so = (it + 1) << 4;
      #pragma unroll
      for (int q = 0; q < 2; q++) {
        gload16(Brow + (size_t)grow[q] * 512 + so + gg[q], &sB[nxt][gdst[q]]);
        gload16(Agr + (size_t)grow[q] * 512 + so + gg[q], &sA[nxt][gdst[q]]);
      }
    }
    bf16x8 Ah[4], Bh[4];
    #pragma unroll
    for (int i = 0; i < 4; i++) {
      Ah[i] = *(const bf16x8*)&sA[cur][fAh[i]];
      Bh[i] = *(const bf16x8*)&sB[cur][fBh[i]];
    }
    #pragma unroll
    for (int i = 0; i < 4; i++)
      #pragma unroll
      for (int j = 0; j < 4; j++)
        acc[i][j] = MFMA16(Ah[i], Bh[j], acc[i][j]);
    __syncthreads();
  }

  // epilogue: D row = lk*4 + reg, col = lr [m89 layout]; optional col stats
  float* Cf = (float*)Cptr;
  u32*   Cu = (u32*)Cptr;
  float st1[4], st2[4];
  #pragma unroll
  for (int j = 0; j < 4; j++) { st1[j] = 0.f; st2[j] = 0.f; }
  #pragma unroll
  for (int j = 0; j < 4; j++) {
    int ocol = n0 + wn + j * 16 + lr;
    float bj = bias[ocol];
    #pragma unroll
    for (int i = 0; i < 4; i++) {
      int orow = m0 + wm + i * 16 + lk * 4;
      #pragma unroll
      for (int reg = 0; reg < 4; reg++) {
        float v = acc[i][j][reg] + bj;
        if (STATS) { st1[j] += v; st2[j] = fmaf(v, v, st2[j]); }
        int row = orow + reg;
        if (OUT == 0) {
          Cf[(size_t)row * CC + ocol] = v;
        } else {
          float pv = __shfl_xor(v, 1);
          if (!(lr & 1))
            Cu[(size_t)row * 512 + (ocol >> 1)] = rne_pack(v, pv);
        }
      }
    }
  }
  if (STATS) {
    float* srb = (float*)&sA[0][0];   // sA is dead after the K-loop
    #pragma unroll
    for (int j = 0; j < 4; j++) {
      st1[j] += __shfl_xor(st1[j], 16, 64);
      st1[j] += __shfl_xor(st1[j], 32, 64);
      st2[j] += __shfl_xor(st2[j], 16, 64);
      st2[j] += __shfl_xor(st2[j], 32, 64);
    }
    if (lk == 0) {
      #pragma unroll
      for (int j = 0; j < 4; j++) {
        srb[wv * 64 + j * 16 + lr]       = st1[j];
        srb[256 + wv * 64 + j * 16 + lr] = st2[j];
      }
    }
    __syncthreads();
    if (t < 128) {
      int ch = t >> 6, c6 = t & 63;
      float a1 = srb[ch * 64 + c6] + srb[(ch + 2) * 64 + c6];
      float a2 = srb[256 + ch * 64 + c6] + srb[256 + (ch + 2) * 64 + c6];
      float2 o = { a1, a2 };
      *(float2*)(partOut + ((size_t)mb * CC + n0 + t) * 2) = o;
    }
  }
}

// conv wrapper with grouped block swizzle (SWZ_G m-tiles x 8 n-tiles per group)
#define SWZ_G 64

template<int OUT, bool STATS>
__global__ __launch_bounds__(256, 2)
void k_mg(const u32* __restrict__ A, const u32* __restrict__ Bp,
          const float* __restrict__ bias, void* __restrict__ Cptr,
          int mtiles, float* __restrict__ partOut)
{
  int id = blockIdx.y * gridDim.x + blockIdx.x;
  int g = id / (SWZ_G * 8);
  int rem = id - g * (SWZ_G * 8);
  int gsz = mtiles - g * SWZ_G; if (gsz > SWZ_G) gsz = SWZ_G;
  int mt = g * SWZ_G + rem % gsz;
  int nt = rem / gsz;
  mg_body<OUT, STATS>(A, Bp, bias, Cptr, mt * 128, nt * 128, partOut, mt);
}

__global__ __launch_bounds__(256, 2)
void k_heads(const u32* __restrict__ ctxp, const u32* __restrict__ wplh,
             const float* __restrict__ lb, float* __restrict__ out)
{
  int p, w;
  head_entry(blockIdx.y, &p, &w);
  mg_body<0, false>(ctxp + (size_t)p * BB * 512,
                    wplh + (size_t)w * 524288,
                    lb + (size_t)w * CC,
                    out + (size_t)blockIdx.y * BB * CC,
                    (blockIdx.x >> 3) * 128, (blockIdx.x & 7) * 128,
                    nullptr, 0);
}

// ---------------------------------------------------------------- launch

extern "C" void kernel_launch(void* const* d_in, const int* in_sizes, int n_in,
                              void* d_out, int out_size, void* d_ws, size_t ws_size,
                              hipStream_t stream)
{
  const float* x   = (const float*)d_in[0];
  const float* bng = (const float*)d_in[1];
  const float* bnb = (const float*)d_in[2];
  const float* cw  = (const float*)d_in[3];
  const float* cb  = (const float*)d_in[4];
  const float* lw  = (const float*)d_in[5];
  const float* lb  = (const float*)d_in[6];
  float* out = (float*)d_out;

  const size_t W = ws_size / 4;           // 4-byte words
  const size_t SZ_WHI  = 3ull * 524288;   // conv weights, RNE hi-only
  const size_t SZ_WPL  = 12ull * 524288;  // head weights, RNE hi-only
  const size_t SZ_PS   = 6400ull * 512;   // pooled RNE hi-only (u32)
  const size_t SZ_CTXP = 6400ull * 512;   // ctx RNE hi-only (u32)
  const size_t SZ_XS   = 50176;
  const size_t SZ_SS   = 25ull * 1024;

  auto need = [&](int pc) -> size_t {
    return SZ_WHI + SZ_WPL
         + 2ull * pc * 2304 * 512           // bufS + bufO (u32)
         + SZ_PS + SZ_CTXP + 2 * SZ_XS + 2 * SZ_SS
         + (size_t)pc * 18 * 1024 * 2;
  };
  int PC;
  if      (W >= need(25)) PC = 25;
  else if (W >= need(5))  PC = 5;
  else                    PC = 1;

  u32*   whi    = (u32*)d_ws;
  u32*   wpl    = whi + SZ_WHI;
  u32*   bufS   = wpl + SZ_WPL;
  u32*   bufO   = bufS + (size_t)PC * 2304 * 512;
  u32*   pooledS= bufO + (size_t)PC * 2304 * 512;
  u32*   ctxp   = pooledS + SZ_PS;
  float* xs1    = (float*)(ctxp + SZ_CTXP);
  float* xs2    = xs1 + SZ_XS;
  float* ssc    = xs2 + SZ_XS;
  float* ssh    = ssc + SZ_SS;
  float* part   = ssh + SZ_SS;

  // weight pre-split: conv + heads, both RNE hi-only
  k_wsplit_rn<<<(int)(SZ_WHI / 256), 256, 0, stream>>>(cw, whi, (int)SZ_WHI);
  k_wsplit_rn<<<(int)(SZ_WPL / 256), 256, 0, stream>>>(lw, wpl, (int)SZ_WPL);
  k_xsums<<<196, 256, 0, stream>>>(x, xs1, xs2);
  k_stats1<<<dim3(25, 4), 256, 0, stream>>>(xs1, xs2, bng, bnb, ssc, ssh);

  for (int pbase = 0; pbase < NP; pbase += PC) {
    const int rows = PC * 2304;
    const int mtiles = PC * 18;
    const dim3 gconv(mtiles, 8);
    // A1: fused transpose + BN1 + relu + RNE -> bufS
    k_tsplit<<<dim3(256, 8), 256, 0, stream>>>(x, ssc, ssh, bufS, pbase, PC);
    // conv1: bufS -> bufO (bf16-pairs), col stats -> part
    k_mg<1, true><<<gconv, 256, 0, stream>>>(bufS, whi, cb, bufO, mtiles, part);
    k_statsfin<<<dim3(PC, 4), 256, 0, stream>>>(part, bng + CC, bnb + CC, ssc, ssh, pbase);
    // A2: BN2+relu+RNE from bufO -> bufS
    k_absplit<<<rows / 8, 256, 0, stream>>>(bufO, ssc, ssh, bufS, pbase);
    // conv2: bufS -> bufO (bf16-pairs), stats -> part
    k_mg<1, true><<<gconv, 256, 0, stream>>>(bufS, whi + 524288, cb + CC,
                                             bufO, mtiles, part);
    k_statsfin<<<dim3(PC, 4), 256, 0, stream>>>(part, bng + 2 * CC, bnb + 2 * CC, ssc, ssh, pbase);
    // BN3+relu+pool from bufO, RNE output -> pooledS slice
    k_pool<<<PC * 256, 256, 0, stream>>>(bufO, ssc, ssh, pooledS, pbase);
  }

  // conv3 over all pooled rows -> ctxp (RNE bf16-pairs, direct)
  k_mg<1, false><<<dim3(50, 8), 256, 0, stream>>>(pooledS, whi + 2 * 524288,
                                                  cb + 2 * CC, ctxp, 50, nullptr);
  // heads: A = ctxp (RNE), B = head weights (RNE), 1 product
  k_heads<<<dim3(16, 120), 256, 0, stream>>>(ctxp, wpl, lb, out);
}